// Round 8
// baseline (300.086 us; speedup 1.0000x reference)
//
#include <hip/hip_runtime.h>
#include <hip/hip_bf16.h>

typedef unsigned short u16;
typedef unsigned int   u32;
typedef unsigned long long u64;
typedef __bf16 bf16x8 __attribute__((ext_vector_type(8)));
typedef float  f32x4  __attribute__((ext_vector_type(4)));

#define S_LEN  2048
#define BATCH  2
#define DMODEL 1024
#define NHEADS 16
#define DKH    64
#define MWORDS (S_LEN/64)
// ATT_SCALE * log2(e): p = exp(s*0.125) = exp2(s * SCALE_LOG2E)
#define SCALE_LOG2E 0.18033688011112042f

__device__ __forceinline__ u16 f2bf(float f){
  u32 x = __builtin_bit_cast(u32, f);
  x += 0x7fffu + ((x >> 16) & 1u);   // RNE
  return (u16)(x >> 16);
}
__device__ __forceinline__ bf16x8 ld8(const u16* p){ return *(const bf16x8*)p; }

// v_cvt_pk_bf16_f32: D[15:0]=bf16(S0), D[31:16]=bf16(S1), RNE — bit-identical
// to f2bf pairs, 1 instruction instead of ~10.
__device__ __forceinline__ u32 pk_bf16(float a, float b){
  u32 d;
  asm("v_cvt_pk_bf16_f32 %0, %1, %2" : "=v"(d) : "v"(a), "v"(b));
  return d;
}

// sign-extended single-bit extract: 0xFFFFFFFF if bit i set, else 0 (1 VALU op)
__device__ __forceinline__ u32 bitmask32(u32 v, int i){
#if __has_builtin(__builtin_amdgcn_sbfe)
  return (u32)__builtin_amdgcn_sbfe((int)v, (u32)i, 1u);
#else
  return 0u - ((v >> i) & 1u);
#endif
}

// async global->LDS, 16B per lane. HW: dest = wave-uniform base + lane*16.
__device__ __forceinline__ void gload16(const u16* g, u16* l){
  __builtin_amdgcn_global_load_lds(
      (const __attribute__((address_space(1))) u32*)(u64)g,
      (__attribute__((address_space(3))) u32*)(u64)l,
      16, 0, 0);
}

// ---- fp32->bf16 bulk conversion + mask bit-packing (round-6 verified) ----
__global__ __launch_bounds__(256) void cvt_kernel(
    const float* __restrict__ a0, const float* __restrict__ a1, const float* __restrict__ a2,
    const float* __restrict__ wi, const float* __restrict__ wo, const int* __restrict__ msk,
    u16* __restrict__ d0, u16* __restrict__ d1, u16* __restrict__ d2,
    u16* __restrict__ dwi, u16* __restrict__ dwo, u64* __restrict__ mbits)
{
  int tid = blockIdx.x*256 + threadIdx.x;
  int stride = gridDim.x*256;
  const int NX = S_LEN*BATCH*DMODEL/4;
  for (int i = tid; i < NX; i += stride){
    f32x4 x0 = ((const f32x4*)a0)[i];
    f32x4 x1 = ((const f32x4*)a1)[i];
    f32x4 x2 = ((const f32x4*)a2)[i];
    ((ushort4*)d0)[i] = make_ushort4(f2bf(x0[0]), f2bf(x0[1]), f2bf(x0[2]), f2bf(x0[3]));
    ((ushort4*)d1)[i] = make_ushort4(f2bf(x1[0]), f2bf(x1[1]), f2bf(x1[2]), f2bf(x1[3]));
    ((ushort4*)d2)[i] = make_ushort4(f2bf(x2[0]), f2bf(x2[1]), f2bf(x2[2]), f2bf(x2[3]));
  }
  const int NWI = 3*DMODEL*DMODEL/4;
  for (int i = tid; i < NWI; i += stride){
    f32x4 x = ((const f32x4*)wi)[i];
    ((ushort4*)dwi)[i] = make_ushort4(f2bf(x[0]), f2bf(x[1]), f2bf(x[2]), f2bf(x[3]));
  }
  const int NWO = DMODEL*DMODEL/4;
  for (int i = tid; i < NWO; i += stride){
    f32x4 x = ((const f32x4*)wo)[i];
    ((ushort4*)dwo)[i] = make_ushort4(f2bf(x[0]), f2bf(x[1]), f2bf(x[2]), f2bf(x[3]));
  }
  int gw   = tid >> 6;
  int lane = threadIdx.x & 63;
  int nwaves = stride >> 6;
  const int NW = BATCH*S_LEN*MWORDS;
  for (int w4 = gw*4; w4 < NW; w4 += nwaves*4){
    int v0 = msk[(size_t)(w4+0)*64 + lane];
    int v1 = msk[(size_t)(w4+1)*64 + lane];
    int v2 = msk[(size_t)(w4+2)*64 + lane];
    int v3 = msk[(size_t)(w4+3)*64 + lane];
    u64 b0 = __ballot(v0 == 0);   // ALLOW bits (mask==1 -> masked out)
    u64 b1 = __ballot(v1 == 0);
    u64 b2 = __ballot(v2 == 0);
    u64 b3 = __ballot(v3 == 0);
    if (lane == 0){
      mbits[w4+0] = b0; mbits[w4+1] = b1;
      mbits[w4+2] = b2; mbits[w4+3] = b3;
    }
  }
}

// ---- 128x128 block GEMM mainloop (C = A @ W^T), K = DMODEL ----
// 2-phase LDS double-buffer; unchanged (verified rounds 5/6).
__device__ __forceinline__ void gemm128_loop(
    const u16* __restrict__ A, const u16* __restrict__ W,
    u16* abuf, u16* bbuf, int tid, f32x4 acc[4][4])
{
  int lane = tid & 63, quad = lane >> 4, r = lane & 15;
  int wv = tid >> 6, wm = (wv & 1)*64, wn = (wv >> 1)*64;
  int c0 = tid, c1 = tid + 256;              // 16B-chunk ids (512 per tile)
  int r0 = c0 >> 2, g0 = ((c0 & 3) ^ (r0 & 3))*8;
  int r1 = c1 >> 2, g1 = ((c1 & 3) ^ (r1 & 3))*8;
  const u16* ga0 = A + (size_t)r0*DMODEL + g0;
  const u16* ga1 = A + (size_t)r1*DMODEL + g1;
  const u16* gb0 = W + (size_t)r0*DMODEL + g0;
  const u16* gb1 = W + (size_t)r1*DMODEL + g1;
  int sw = (quad ^ (r & 3))*8;               // de-swizzle for fragment reads

  auto stage = [&](int bu, int k0){
    u16* ab = abuf + bu*(128*32);
    u16* bb = bbuf + bu*(128*32);
    gload16(ga0 + k0, ab + c0*8);
    gload16(ga1 + k0, ab + c1*8);
    gload16(gb0 + k0, bb + c0*8);
    gload16(gb1 + k0, bb + c1*8);
  };
  auto step = [&](int bu){
    const u16* ab = abuf + bu*(128*32);
    const u16* bb = bbuf + bu*(128*32);
    bf16x8 af[4], bfr[4];
    #pragma unroll
    for (int i = 0; i < 4; ++i) af[i]  = ld8(&ab[(wm + i*16 + r)*32 + sw]);
    #pragma unroll
    for (int i = 0; i < 4; ++i) bfr[i] = ld8(&bb[(wn + i*16 + r)*32 + sw]);
    #pragma unroll
    for (int mi = 0; mi < 4; ++mi)
      #pragma unroll
      for (int ni = 0; ni < 4; ++ni)
        acc[mi][ni] = __builtin_amdgcn_mfma_f32_16x16x32_bf16(af[mi], bfr[ni], acc[mi][ni], 0,0,0);
  };

  stage(0, 0);
  __syncthreads();                           // prologue tile visible
  for (int k0 = 0; k0 < DMODEL; k0 += 64){
    stage(1, k0 + 32);                       // prefetch in flight over compute
    step(0);
    __syncthreads();                         // drains vmcnt: buf1 staged, buf0 reads done
    if (k0 + 64 < DMODEL) stage(0, k0 + 64);
    step(1);
    __syncthreads();
  }
}

// QKV projection: grid (32, 24). q,k -> (B,H,S,DK); v -> transposed (B,H,DK,S)
__global__ __launch_bounds__(256) void qkv_proj_kernel(
    const u16* __restrict__ xq, const u16* __restrict__ xk, const u16* __restrict__ xv,
    const u16* __restrict__ w, const float* __restrict__ bias,
    u16* __restrict__ q_ws, u16* __restrict__ k_ws, u16* __restrict__ vt_ws)
{
  __shared__ __align__(16) u16 abuf[2*128*32];
  __shared__ __align__(16) u16 bbuf[2*128*32];
  int tid = threadIdx.x;
  int lane = tid & 63, quad = lane >> 4, r = lane & 15;
  int wv = tid >> 6, wm = (wv & 1)*64, wn = (wv >> 1)*64;
  int m0 = blockIdx.x*128, n0 = blockIdx.y*128;
  int t = n0 >> 10;                          // 0=q,1=k,2=v (block-uniform; 1024%128==0)
  const u16* X = (t == 0) ? xq : (t == 1) ? xk : xv;

  f32x4 acc[4][4] = {};
  gemm128_loop(X + (size_t)m0*DMODEL, w + (size_t)n0*DMODEL, abuf, bbuf, tid, acc);

  int mbase = m0 + wm, nbase = n0 + wn;
  #pragma unroll
  for (int ni = 0; ni < 4; ++ni){
    int n  = nbase + ni*16 + r;
    float bv = bias[n];
    int nn = n & (DMODEL-1);
    int h = nn >> 6, dk = nn & 63;
    #pragma unroll
    for (int mi = 0; mi < 4; ++mi){
      #pragma unroll
      for (int reg = 0; reg < 4; ++reg){
        int m = mbase + mi*16 + quad*4 + reg;
        int s = m >> 1, b = m & 1;           // m = s*B + b
        u16 hv = f2bf(acc[mi][ni][reg] + bv);
        size_t bh = (size_t)(b*NHEADS + h);
        if (t == 0)      q_ws [(bh*S_LEN + s)*DKH + dk] = hv;
        else if (t == 1) k_ws [(bh*S_LEN + s)*DKH + dk] = hv;
        else             vt_ws[(bh*DKH + dk)*S_LEN + s] = hv;
      }
    }
  }
}

// Flash attention — IN-BLOCK SPLIT-K.
// Decomposition ceiling found: 65536 rows / 16 per wave = 4096 waves = 16
// waves/CU max. Fix: 16-wave blocks (1024 thr); waves z=0 do k in [0,1024),
// z=1 do k in [1024,2048) for the SAME 128 q-rows. 8192 waves = 32/CU (100%).
// KVBLK=32 tiles; per-z K/V double-buffers (32KB) + 16 pbufs (16KB) = 48KB.
// Final combine in LDS (z=1 writes o,l partials over dead K/V space; one
// barrier; z=0 adds, divides, stores). Element math bit-identical; only new
// rounding is one f32 reassociation at the k=1024 boundary (~1e-7 rel).
// Swizzle involutions (re-derived, round-trip checked):
//   kbuf [32][64]: chunk^(row&7), rows read 16c+r ≡ r (mod 8)  ✓
//   vbuf [64][32]: chunk^(row&3), rows read tt*16+r ≡ r (mod 4) ✓
//   pbuf [16][32]: write chunk (2c+(q>>1))^(r&3), read quad^(r&3);
//     element k=16c+4q'+i lands at chunk 2c+(q'>>1), off (q'&1)*4+i ✓
__global__ __launch_bounds__(1024, 8) void attn_kernel(
    const u16* __restrict__ q_ws, const u16* __restrict__ k_ws, const u16* __restrict__ vt_ws,
    const u64* __restrict__ mbits, u16* __restrict__ x_ws)
{
  // smem carve: [0,16K) kbuf(z,bu) 4 tiles x 4KB; [16K,32K) vbuf(z,bu);
  // [32K,48K) pbuf per wv16 (512 u16 each). Combine overlays [0,32K) as f32
  // o-scratch (8 slots x 4KB) and [32K,..) as l-scratch.
  __shared__ __align__(16) u16 smem[3*8192];
  int tid  = threadIdx.x;
  int wv16 = tid >> 6;                       // 0..15
  int z    = wv16 >> 3;                      // 0,1 : k-half
  int wv   = wv16 & 7;                       // 0..7 : q-row group
  int lane = tid & 63;
  int quad = lane >> 4, r = lane & 15;
  int kz   = z << 10;                        // z*1024

  // bijective XCD swizzle: 4 bh x 16 xt per XCD (unchanged)
  int lin  = blockIdx.y * 16 + blockIdx.x;   // grid (16,32) = 512
  int xcd  = lin & 7, slot = lin >> 3;
  int bh   = (xcd << 2) | (slot >> 4);
  int xt   = slot & 15;
  int b  = bh >> 4, h = bh & 15;
  int i0 = (xt*8 + wv) * 16;

  const u16* Q  = q_ws  + (size_t)bh*S_LEN*DKH;
  const u16* K  = k_ws  + (size_t)bh*S_LEN*DKH;
  const u16* Vt = vt_ws + (size_t)bh*DKH*S_LEN;
  const u64* MB = mbits + ((size_t)b*S_LEN + (i0 + r))*MWORDS;

  // staging roles (wave-uniform): z-group waves 0-3 stage K, 4-7 stage V.
  // K tile [32][64] = 256 chunks; V tile [64][32] = 256 chunks; 512 thr/z.
  int lt   = tid & 511;
  bool isK = lt < 256;
  int krow = lt >> 3,  kch = lt & 7;         // K: 32 rows x 8 chunks
  int vl   = lt & 255;
  int vrow = vl >> 3 ? vl >> 2 : vl >> 2;    // (kept simple below)
  vrow = vl >> 2;  int vch = vl & 3;         // V: 64 rows x 4 chunks
  const u16* gK = K  + (size_t)krow*DKH   + kch*8;   // + kbase*DKH
  const u16* gV = Vt + (size_t)vrow*S_LEN + vch*8;   // + kbase
  u16* kbz = smem          + (z*2)*2048;     // + bu*2048
  u16* vbz = smem + 8192   + (z*2)*2048;
  u16* ldst0 = isK ? (kbz + krow*64 + ((kch ^ (krow & 7))*8))
                   : (vbz + vrow*32 + ((vch ^ (vrow & 3))*8));
  u16* ldst1 = ldst0 + 2048;

  const u16* qrow = Q + (size_t)(i0 + r)*DKH + quad*8;
  bf16x8 qf0 = ld8(qrow), qf1 = ld8(qrow + 32);

  int m7   = r & 7, m3 = r & 3;
  int ksw0 = (quad ^ m7) * 8;                // kbuf chunk (of 8)
  int ksw1 = ksw0 ^ 32;
  int psw  = (quad ^ m3) * 8;                // pbuf/vbuf chunk (of 4)
  int pwh  = (quad & 1) * 4;                 // within-chunk half for P writes
  int pwq  = quad >> 1;

  float l_part = 0.f;
  f32x4 o[4] = {};
  f32x4 z4 = {0.f, 0.f, 0.f, 0.f};
  u16* pl = smem + 16384 + wv16*512;

  bf16x8 sa, sb;
  auto gload = [&](int kbase)->bf16x8 {
    return isK ? ld8(gK + (size_t)kbase*DKH) : ld8(gV + kbase);
  };
  auto compute = [&](int bu, u64 mb, int sh){
    const u16* kb = kbz + bu*2048;
    const u16* vb = vbz + bu*2048;
    float p[8];
    #pragma unroll
    for (int c = 0; c < 2; ++c){
      int rowb = (16*c + r)*64;
      bf16x8 ka = ld8(&kb[rowb + ksw0]);
      bf16x8 k8 = ld8(&kb[rowb + ksw1]);
      __builtin_amdgcn_s_setprio(1);
      f32x4 s = __builtin_amdgcn_mfma_f32_16x16x32_bf16(ka, qf0, z4, 0,0,0);
      s       = __builtin_amdgcn_mfma_f32_16x16x32_bf16(k8, qf1, s, 0,0,0);
      __builtin_amdgcn_s_setprio(0);
      u32 mc = (u32)(mb >> (sh + 16*c + 4*quad));
      #pragma unroll
      for (int i = 0; i < 4; ++i){
        float ev = __builtin_amdgcn_exp2f(s[i]*SCALE_LOG2E);
        p[c*4+i] = __builtin_bit_cast(float,
                     __builtin_bit_cast(u32, ev) & bitmask32(mc, i));
        l_part += p[c*4+i];
      }
    }
    #pragma unroll
    for (int c = 0; c < 2; ++c){
      u32 k0 = pk_bf16(p[c*4+0], p[c*4+1]);
      u32 k1 = pk_bf16(p[c*4+2], p[c*4+3]);
      int pwc = (2*c + pwq) ^ m3;            // disjoint bits: exact XOR decomp
      *(uint2*)&pl[r*32 + pwc*8 + pwh] = make_uint2(k0, k1);
    }
    asm volatile("s_waitcnt lgkmcnt(0)" ::: "memory");
    bf16x8 pf = ld8(&pl[r*32 + psw]);
    __builtin_amdgcn_s_setprio(1);
    #pragma unroll
    for (int tt = 0; tt < 4; ++tt){
      bf16x8 vf = ld8(&vb[(tt*16 + r)*32 + psw]);
      o[tt] = __builtin_amdgcn_mfma_f32_16x16x32_bf16(pf, vf, o[tt], 0,0,0);
    }
    __builtin_amdgcn_s_setprio(0);
  };

  // prologue: tile kz -> buf0; tile kz+32 loads in flight
  sa = gload(kz);
  *(bf16x8*)ldst0 = sa;
  sb = gload(kz + 32);
  __syncthreads();

  for (int j0 = 0; j0 < 1024; j0 += 64){
    u64 mb = MB[(kz + j0) >> 6];
    *(bf16x8*)ldst1 = sb;                    // tile j0+32 -> buf1
    if (j0 + 64 < 1024) sa = gload(kz + j0 + 64);
    compute(0, mb, 0);
    __syncthreads();                         // buf1 visible; buf0 reads done
    if (j0 + 64 < 1024) *(bf16x8*)ldst0 = sa;
    if (j0 + 96 < 1024) sb = gload(kz + j0 + 96);
    compute(1, mb, 32);
    __syncthreads();
  }

  // per-z row sums (quad reduction)
  l_part += __shfl_xor(l_part, 16, 64);
  l_part += __shfl_xor(l_part, 32, 64);

  // combine: z=1 -> LDS scratch (overlays dead K/V + pbuf), z=0 finishes.
  float* osc = (float*)smem;                 // 8 slots x [16][64] f32
  float* lsc = (float*)(smem + 16384);       // 8 x 16 f32
  if (z == 1){
    float* sl = osc + wv*1024;
    #pragma unroll
    for (int tt = 0; tt < 4; ++tt)
      #pragma unroll
      for (int reg = 0; reg < 4; ++reg)
        sl[(quad*4 + reg)*64 + tt*16 + r] = o[tt][reg];
    if (quad == 0) lsc[wv*16 + r] = l_part;
  }
  __syncthreads();
  if (z == 0){
    float* sl = osc + wv*1024;
    #pragma unroll
    for (int tt = 0; tt < 4; ++tt)
      #pragma unroll
      for (int reg = 0; reg < 4; ++reg)
        o[tt][reg] += sl[(quad*4 + reg)*64 + tt*16 + r];
    float lt_ = l_part + lsc[wv*16 + r];
    float l0 = 1.f/__shfl(lt_, quad*4+0, 64);
    float l1 = 1.f/__shfl(lt_, quad*4+1, 64);
    float l2 = 1.f/__shfl(lt_, quad*4+2, 64);
    float l3 = 1.f/__shfl(lt_, quad*4+3, 64);
    #pragma unroll
    for (int tt = 0; tt < 4; ++tt){
      int col = h*DKH + tt*16 + r;
      x_ws[((size_t)(i0 + quad*4 + 0)*BATCH + b)*DMODEL + col] = f2bf(o[tt][0]*l0);
      x_ws[((size_t)(i0 + quad*4 + 1)*BATCH + b)*DMODEL + col] = f2bf(o[tt][1]*l1);
      x_ws[((size_t)(i0 + quad*4 + 2)*BATCH + b)*DMODEL + col] = f2bf(o[tt][2]*l2);
      x_ws[((size_t)(i0 + quad*4 + 3)*BATCH + b)*DMODEL + col] = f2bf(o[tt][3]*l3);
    }
  }
}

// Out projection: grid (32, 8). x_ws(bf16) @ Wout.T(bf16) + bout -> fp32
__global__ __launch_bounds__(256) void out_proj_kernel(
    const u16* __restrict__ x, const u16* __restrict__ w, const float* __restrict__ bias,
    float* __restrict__ out)
{
  __shared__ __align__(16) u16 abuf[2*128*32];
  __shared__ __align__(16) u16 bbuf[2*128*32];
  int tid = threadIdx.x;
  int lane = tid & 63, quad = lane >> 4, r = lane & 15;
  int wv = tid >> 6, wm = (wv & 1)*64, wn = (wv >> 1)*64;
  int m0 = blockIdx.x*128, n0 = blockIdx.y*128;

  f32x4 acc[4][4] = {};
  gemm128_loop(x + (size_t)m0*DMODEL, w + (size_t)n0*DMODEL, abuf, bbuf, tid, acc);

  int mbase = m0 + wm, nbase = n0 + wn;
  #pragma unroll
  for (int ni = 0; ni < 4; ++ni){
    int n = nbase + ni*16 + r;
    float bv = bias[n];
    #pragma unroll
    for (int mi = 0; mi < 4; ++mi){
      #pragma unroll
      for (int reg = 0; reg < 4; ++reg){
        int m = mbase + mi*16 + quad*4 + reg;
        out[(size_t)m*DMODEL + n] = acc[mi][ni][reg] + bv;
      }
    }
  }
}

extern "C" void kernel_launch(void* const* d_in, const int* in_sizes, int n_in,
                              void* d_out, int out_size, void* d_ws, size_t ws_size,
                              hipStream_t stream) {
  (void)in_sizes; (void)n_in; (void)out_size; (void)ws_size;
  const float* query = (const float*)d_in[0];
  const float* key   = (const float*)d_in[1];
  const float* value = (const float*)d_in[2];
  const int*   mask  = (const int*)d_in[3];
  const float* w_in  = (const float*)d_in[4];
  const float* b_in  = (const float*)d_in[5];
  const float* w_out = (const float*)d_in[6];
  const float* b_out = (const float*)d_in[7];
  float* out = (float*)d_out;

  const size_t TSZ = (size_t)BATCH*NHEADS*S_LEN*DKH;
  const size_t XSZ = (size_t)S_LEN*BATCH*DMODEL;
  u16* q_ws  = (u16*)d_ws;
  u16* k_ws  = q_ws  + TSZ;
  u16* vt_ws = k_ws  + TSZ;
  u16* x_ws  = vt_ws + TSZ;
  u16* xq_bf = x_ws  + XSZ;
  u16* xk_bf = xq_bf + XSZ;
  u16* xv_bf = xk_bf + XSZ;
  u16* wi_bf = xv_bf + XSZ;
  u16* wo_bf = wi_bf + (size_t)3*DMODEL*DMODEL;
  u64* mb_ws = (u64*)(wo_bf + (size_t)DMODEL*DMODEL);

  cvt_kernel<<<1024, 256, 0, stream>>>(query, key, value, w_in, w_out, mask,
                                       xq_bf, xk_bf, xv_bf, wi_bf, wo_bf, mb_ws);
  qkv_proj_kernel<<<dim3(32, 24), 256, 0, stream>>>(xq_bf, xk_bf, xv_bf, wi_bf, b_in,
                                                    q_ws, k_ws, vt_ws);
  attn_kernel<<<dim3(16, 32), 1024, 0, stream>>>(q_ws, k_ws, vt_ws, mb_ws, x_ws);
  out_proj_kernel<<<dim3(32, 8), 256, 0, stream>>>(x_ws, wo_bf, b_out, out);
}

// Round 10
// 252.333 us; speedup vs baseline: 1.1892x; 1.1892x over previous
//
#include <hip/hip_runtime.h>
#include <hip/hip_bf16.h>

typedef unsigned short u16;
typedef unsigned int   u32;
typedef unsigned long long u64;
typedef __bf16 bf16x8 __attribute__((ext_vector_type(8)));
typedef float  f32x4  __attribute__((ext_vector_type(4)));

#define S_LEN  2048
#define BATCH  2
#define DMODEL 1024
#define NHEADS 16
#define DKH    64
#define MWORDS (S_LEN/64)
// ATT_SCALE * log2(e): p = exp(s*0.125) = exp2(s * SCALE_LOG2E)
#define SCALE_LOG2E 0.18033688011112042f

__device__ __forceinline__ u16 f2bf(float f){
  u32 x = __builtin_bit_cast(u32, f);
  x += 0x7fffu + ((x >> 16) & 1u);   // RNE
  return (u16)(x >> 16);
}
__device__ __forceinline__ bf16x8 ld8(const u16* p){ return *(const bf16x8*)p; }

// v_cvt_pk_bf16_f32: RNE, bit-identical to f2bf pairs.
__device__ __forceinline__ u32 pk_bf16(float a, float b){
  u32 d;
  asm("v_cvt_pk_bf16_f32 %0, %1, %2" : "=v"(d) : "v"(a), "v"(b));
  return d;
}

// sign-extended single-bit extract: 0xFFFFFFFF if bit i set, else 0
__device__ __forceinline__ u32 bitmask32(u32 v, int i){
#if __has_builtin(__builtin_amdgcn_sbfe)
  return (u32)__builtin_amdgcn_sbfe((int)v, (u32)i, 1u);
#else
  return 0u - ((v >> i) & 1u);
#endif
}

// async global->LDS, 16B per lane. HW: dest = wave-uniform base + lane*16.
__device__ __forceinline__ void gload16(const u16* g, u16* l){
  __builtin_amdgcn_global_load_lds(
      (const __attribute__((address_space(1))) u32*)(u64)g,
      (__attribute__((address_space(3))) u32*)(u64)l,
      16, 0, 0);
}

// ---- fp32->bf16 bulk conversion + mask bit-packing (verified round 6) ----
__global__ __launch_bounds__(256) void cvt_kernel(
    const float* __restrict__ a0, const float* __restrict__ a1, const float* __restrict__ a2,
    const float* __restrict__ wi, const float* __restrict__ wo, const int* __restrict__ msk,
    u16* __restrict__ d0, u16* __restrict__ d1, u16* __restrict__ d2,
    u16* __restrict__ dwi, u16* __restrict__ dwo, u64* __restrict__ mbits)
{
  int tid = blockIdx.x*256 + threadIdx.x;
  int stride = gridDim.x*256;
  const int NX = S_LEN*BATCH*DMODEL/4;
  for (int i = tid; i < NX; i += stride){
    f32x4 x0 = ((const f32x4*)a0)[i];
    f32x4 x1 = ((const f32x4*)a1)[i];
    f32x4 x2 = ((const f32x4*)a2)[i];
    ((ushort4*)d0)[i] = make_ushort4(f2bf(x0[0]), f2bf(x0[1]), f2bf(x0[2]), f2bf(x0[3]));
    ((ushort4*)d1)[i] = make_ushort4(f2bf(x1[0]), f2bf(x1[1]), f2bf(x1[2]), f2bf(x1[3]));
    ((ushort4*)d2)[i] = make_ushort4(f2bf(x2[0]), f2bf(x2[1]), f2bf(x2[2]), f2bf(x2[3]));
  }
  const int NWI = 3*DMODEL*DMODEL/4;
  for (int i = tid; i < NWI; i += stride){
    f32x4 x = ((const f32x4*)wi)[i];
    ((ushort4*)dwi)[i] = make_ushort4(f2bf(x[0]), f2bf(x[1]), f2bf(x[2]), f2bf(x[3]));
  }
  const int NWO = DMODEL*DMODEL/4;
  for (int i = tid; i < NWO; i += stride){
    f32x4 x = ((const f32x4*)wo)[i];
    ((ushort4*)dwo)[i] = make_ushort4(f2bf(x[0]), f2bf(x[1]), f2bf(x[2]), f2bf(x[3]));
  }
  int gw   = tid >> 6;
  int lane = threadIdx.x & 63;
  int nwaves = stride >> 6;
  const int NW = BATCH*S_LEN*MWORDS;
  for (int w4 = gw*4; w4 < NW; w4 += nwaves*4){
    int v0 = msk[(size_t)(w4+0)*64 + lane];
    int v1 = msk[(size_t)(w4+1)*64 + lane];
    int v2 = msk[(size_t)(w4+2)*64 + lane];
    int v3 = msk[(size_t)(w4+3)*64 + lane];
    u64 b0 = __ballot(v0 == 0);   // ALLOW bits (mask==1 -> masked out)
    u64 b1 = __ballot(v1 == 0);
    u64 b2 = __ballot(v2 == 0);
    u64 b3 = __ballot(v3 == 0);
    if (lane == 0){
      mbits[w4+0] = b0; mbits[w4+1] = b1;
      mbits[w4+2] = b2; mbits[w4+3] = b3;
    }
  }
}

// ---- 128x128 block GEMM mainloop (C = A @ W^T), K = DMODEL ----
// 2-phase LDS double-buffer; unchanged (verified rounds 5/6).
__device__ __forceinline__ void gemm128_loop(
    const u16* __restrict__ A, const u16* __restrict__ W,
    u16* abuf, u16* bbuf, int tid, f32x4 acc[4][4])
{
  int lane = tid & 63, quad = lane >> 4, r = lane & 15;
  int wv = tid >> 6, wm = (wv & 1)*64, wn = (wv >> 1)*64;
  int c0 = tid, c1 = tid + 256;              // 16B-chunk ids (512 per tile)
  int r0 = c0 >> 2, g0 = ((c0 & 3) ^ (r0 & 3))*8;
  int r1 = c1 >> 2, g1 = ((c1 & 3) ^ (r1 & 3))*8;
  const u16* ga0 = A + (size_t)r0*DMODEL + g0;
  const u16* ga1 = A + (size_t)r1*DMODEL + g1;
  const u16* gb0 = W + (size_t)r0*DMODEL + g0;
  const u16* gb1 = W + (size_t)r1*DMODEL + g1;
  int sw = (quad ^ (r & 3))*8;               // de-swizzle for fragment reads

  auto stage = [&](int bu, int k0){
    u16* ab = abuf + bu*(128*32);
    u16* bb = bbuf + bu*(128*32);
    gload16(ga0 + k0, ab + c0*8);
    gload16(ga1 + k0, ab + c1*8);
    gload16(gb0 + k0, bb + c0*8);
    gload16(gb1 + k0, bb + c1*8);
  };
  auto step = [&](int bu){
    const u16* ab = abuf + bu*(128*32);
    const u16* bb = bbuf + bu*(128*32);
    bf16x8 af[4], bfr[4];
    #pragma unroll
    for (int i = 0; i < 4; ++i) af[i]  = ld8(&ab[(wm + i*16 + r)*32 + sw]);
    #pragma unroll
    for (int i = 0; i < 4; ++i) bfr[i] = ld8(&bb[(wn + i*16 + r)*32 + sw]);
    #pragma unroll
    for (int mi = 0; mi < 4; ++mi)
      #pragma unroll
      for (int ni = 0; ni < 4; ++ni)
        acc[mi][ni] = __builtin_amdgcn_mfma_f32_16x16x32_bf16(af[mi], bfr[ni], acc[mi][ni], 0,0,0);
  };

  stage(0, 0);
  __syncthreads();                           // prologue tile visible
  for (int k0 = 0; k0 < DMODEL; k0 += 64){
    stage(1, k0 + 32);                       // prefetch in flight over compute
    step(0);
    __syncthreads();                         // drains vmcnt: buf1 staged, buf0 reads done
    if (k0 + 64 < DMODEL) stage(0, k0 + 64);
    step(1);
    __syncthreads();
  }
}

// QKV projection: grid (32, 24). q,k -> (B,H,S,DK); v -> transposed (B,H,DK,S)
__global__ __launch_bounds__(256) void qkv_proj_kernel(
    const u16* __restrict__ xq, const u16* __restrict__ xk, const u16* __restrict__ xv,
    const u16* __restrict__ w, const float* __restrict__ bias,
    u16* __restrict__ q_ws, u16* __restrict__ k_ws, u16* __restrict__ vt_ws)
{
  __shared__ __align__(16) u16 abuf[2*128*32];
  __shared__ __align__(16) u16 bbuf[2*128*32];
  int tid = threadIdx.x;
  int lane = tid & 63, quad = lane >> 4, r = lane & 15;
  int wv = tid >> 6, wm = (wv & 1)*64, wn = (wv >> 1)*64;
  int m0 = blockIdx.x*128, n0 = blockIdx.y*128;
  int t = n0 >> 10;                          // 0=q,1=k,2=v (block-uniform; 1024%128==0)
  const u16* X = (t == 0) ? xq : (t == 1) ? xk : xv;

  f32x4 acc[4][4] = {};
  gemm128_loop(X + (size_t)m0*DMODEL, w + (size_t)n0*DMODEL, abuf, bbuf, tid, acc);

  int mbase = m0 + wm, nbase = n0 + wn;
  #pragma unroll
  for (int ni = 0; ni < 4; ++ni){
    int n  = nbase + ni*16 + r;
    float bv = bias[n];
    int nn = n & (DMODEL-1);
    int h = nn >> 6, dk = nn & 63;
    #pragma unroll
    for (int mi = 0; mi < 4; ++mi){
      #pragma unroll
      for (int reg = 0; reg < 4; ++reg){
        int m = mbase + mi*16 + quad*4 + reg;
        int s = m >> 1, b = m & 1;           // m = s*B + b
        u16 hv = f2bf(acc[mi][ni][reg] + bv);
        size_t bh = (size_t)(b*NHEADS + h);
        if (t == 0)      q_ws [(bh*S_LEN + s)*DKH + dk] = hv;
        else if (t == 1) k_ws [(bh*S_LEN + s)*DKH + dk] = hv;
        else             vt_ws[(bh*DKH + dk)*S_LEN + s] = hv;
      }
    }
  }
}

// Flash attention — ROUND-6 VERIFIED BASE (63.9us, 56 VGPR, no spill) with one
// addition: softmax denominator l via MFMA row-sum instead of VALU adds.
//   l4 = mfma(pf, ones, l4): B=all-ones -> every D column = row-sum of P.
//   D[row=quad*4+reg][col=r] -> l4[reg] = l[i0+quad*4+reg], uniform over r,
//   exactly matching o[tt][reg]'s row => epilogue needs NO shuffles.
// Replaces 512 VALU adds + 6 shuffles per wave with 64 MFMAs on the 21%-idle
// matrix pipe. Numerics: l sums bf16-rounded p (RNE, zero-mean over ~2048
// terms, ~1e-4 rel) vs f32 p before.
// ROUND-8 LESSON (do not repeat): __launch_bounds__(1024,8) split-K capped
// VGPR at 32 -> accumulator spill -> 198MB scratch writes, attn 112us.
__global__ __launch_bounds__(512) void attn_kernel(
    const u16* __restrict__ q_ws, const u16* __restrict__ k_ws, const u16* __restrict__ vt_ws,
    const u64* __restrict__ mbits, u16* __restrict__ x_ws)
{
  __shared__ __align__(16) u16 kbuf[2][64*64];
  __shared__ __align__(16) u16 vbuf[2][64*64];
  __shared__ __align__(16) u16 pbuf[8][16*64];
  int tid  = threadIdx.x;
  int wv   = tid >> 6;                       // 0..7
  int lane = tid & 63;
  int quad = lane >> 4, r = lane & 15;

  // bijective XCD swizzle: 4 bh x 16 xt per XCD (KV set 2MB < 4MB L2)
  int lin  = blockIdx.y * 16 + blockIdx.x;   // grid (16,32) = 512
  int xcd  = lin & 7, slot = lin >> 3;       // slot 0..63
  int bh   = (xcd << 2) | (slot >> 4);
  int xt   = slot & 15;
  int b  = bh >> 4, h = bh & 15;
  int i0 = (xt*8 + wv) * 16;

  const u16* Q  = q_ws  + (size_t)bh*S_LEN*DKH;
  const u16* K  = k_ws  + (size_t)bh*S_LEN*DKH;
  const u16* Vt = vt_ws + (size_t)bh*DKH*S_LEN;
  const u64* MB = mbits + ((size_t)b*S_LEN + (i0 + r))*MWORDS;

  // staging: 512 threads x 16B = one full 64x64 tile per buffer
  int sr  = tid >> 3;                        // row 0..63
  int sc8 = (tid & 7) * 8;                   // logical element col
  int ssw = ((tid & 7) ^ (sr & 7)) * 8;      // swizzled element col
  const u16* Kp = K  + (size_t)sr*DKH   + sc8;
  const u16* Vp = Vt + (size_t)sr*S_LEN + sc8;

  const u16* qrow = Q + (size_t)(i0 + r)*DKH + quad*8;
  bf16x8 qf0 = ld8(qrow), qf1 = ld8(qrow + 32);

  // swizzled per-lane read offsets (element units)
  int m7   = r & 7;
  int ksw0 = (quad ^ m7) * 8;                // lo chunk
  int ksw1 = ksw0 ^ 32;                      // chunk^4 == +/-32 elements
  int pw0  = ((quad >> 1) ^ m7) * 8 + (quad & 1)*4;  // c=0 write base

  // all-ones B fragment for the l row-sum MFMA
  bf16x8 ones;
  #pragma unroll
  for (int i = 0; i < 8; ++i) ones[i] = (__bf16)1.0f;

  f32x4 l4 = {};                             // l[i0+quad*4+reg] accumulator
  f32x4 o[4] = {};
  f32x4 z = {0.f, 0.f, 0.f, 0.f};
  u16* pl = pbuf[wv];

  bf16x8 ka_, va_, kb_, vb_;
  auto loadset = [&](bf16x8& kv, bf16x8& vv, int j0){
    kv = ld8(Kp + (size_t)j0*DKH);
    vv = ld8(Vp + j0);
  };
  auto storeset = [&](int bu, bf16x8 kv, bf16x8 vv){
    *(bf16x8*)&kbuf[bu][sr*64 + ssw] = kv;
    *(bf16x8*)&vbuf[bu][sr*64 + ssw] = vv;
  };
  auto compute = [&](int bu, u64 mb){
    const u16* kb = kbuf[bu];
    const u16* vb = vbuf[bu];
    float p[16];
    #pragma unroll
    for (int c = 0; c < 4; ++c){
      int rowb = (16*c + r)*64;
      bf16x8 ka = ld8(&kb[rowb + ksw0]);
      bf16x8 k8 = ld8(&kb[rowb + ksw1]);
      __builtin_amdgcn_s_setprio(1);
      f32x4 s = __builtin_amdgcn_mfma_f32_16x16x32_bf16(ka, qf0, z, 0,0,0);
      s       = __builtin_amdgcn_mfma_f32_16x16x32_bf16(k8, qf1, s, 0,0,0);
      __builtin_amdgcn_s_setprio(0);
      u32 mc = (u32)(mb >> (16*c + 4*quad));
      #pragma unroll
      for (int i = 0; i < 4; ++i){
        float ev = __builtin_amdgcn_exp2f(s[i]*SCALE_LOG2E);
        p[c*4+i] = __builtin_bit_cast(float,
                     __builtin_bit_cast(u32, ev) & bitmask32(mc, i));
      }
    }
    #pragma unroll
    for (int c = 0; c < 4; ++c){
      u32 k0 = pk_bf16(p[c*4+0], p[c*4+1]);
      u32 k1 = pk_bf16(p[c*4+2], p[c*4+3]);
      // chunk 2c+(q>>1) ^ (r&7): disjoint bits -> exact XOR decomposition
      *(uint2*)&pl[r*64 + ((pw0 & ~7) ^ (2*c*8)) + (pw0 & 7)] = make_uint2(k0, k1);
    }
    asm volatile("s_waitcnt lgkmcnt(0)" ::: "memory");
    bf16x8 pf0 = ld8(&pl[r*64 + ksw0]);      // logical chunk quad
    bf16x8 pf1 = ld8(&pl[r*64 + ksw1]);      // logical chunk quad+4
    __builtin_amdgcn_s_setprio(1);
    l4 = __builtin_amdgcn_mfma_f32_16x16x32_bf16(pf0, ones, l4, 0,0,0);
    l4 = __builtin_amdgcn_mfma_f32_16x16x32_bf16(pf1, ones, l4, 0,0,0);
    #pragma unroll
    for (int tt = 0; tt < 4; ++tt){
      int rowb = (tt*16 + r)*64;
      bf16x8 va = ld8(&vb[rowb + ksw0]);
      bf16x8 v8 = ld8(&vb[rowb + ksw1]);
      o[tt] = __builtin_amdgcn_mfma_f32_16x16x32_bf16(pf0, va, o[tt], 0,0,0);
      o[tt] = __builtin_amdgcn_mfma_f32_16x16x32_bf16(pf1, v8, o[tt], 0,0,0);
    }
    __builtin_amdgcn_s_setprio(0);
  };

  // prologue: tile0 staged to buf0; tile1 loads in flight
  loadset(ka_, va_, 0);
  storeset(0, ka_, va_);
  loadset(kb_, vb_, 64);
  __syncthreads();

  for (int j0 = 0; j0 < S_LEN; j0 += 128){
    storeset(1, kb_, vb_);
    if (j0 + 128 < S_LEN) loadset(ka_, va_, j0 + 128);
    compute(0, MB[j0 >> 6]);
    __syncthreads();                         // buf1 visible; buf0 reads done
    if (j0 + 128 < S_LEN) storeset(0, ka_, va_);
    if (j0 + 192 < S_LEN) loadset(kb_, vb_, j0 + 192);
    compute(1, MB[(j0 >> 6) + 1]);
    __syncthreads();
  }

  // l4[reg] = l[i0+quad*4+reg] (uniform across r): no shuffles needed.
  float l0 = 1.f/l4[0];
  float l1 = 1.f/l4[1];
  float l2 = 1.f/l4[2];
  float l3 = 1.f/l4[3];
  #pragma unroll
  for (int tt = 0; tt < 4; ++tt){
    int col = h*DKH + tt*16 + r;
    x_ws[((size_t)(i0 + quad*4 + 0)*BATCH + b)*DMODEL + col] = f2bf(o[tt][0]*l0);
    x_ws[((size_t)(i0 + quad*4 + 1)*BATCH + b)*DMODEL + col] = f2bf(o[tt][1]*l1);
    x_ws[((size_t)(i0 + quad*4 + 2)*BATCH + b)*DMODEL + col] = f2bf(o[tt][2]*l2);
    x_ws[((size_t)(i0 + quad*4 + 3)*BATCH + b)*DMODEL + col] = f2bf(o[tt][3]*l3);
  }
}

// Out projection: grid (32, 8). x_ws(bf16) @ Wout.T(bf16) + bout -> fp32
__global__ __launch_bounds__(256) void out_proj_kernel(
    const u16* __restrict__ x, const u16* __restrict__ w, const float* __restrict__ bias,
    float* __restrict__ out)
{
  __shared__ __align__(16) u16 abuf[2*128*32];
  __shared__ __align__(16) u16 bbuf[2*128*32];
  int tid = threadIdx.x;
  int lane = tid & 63, quad = lane >> 4, r = lane & 15;
  int wv = tid >> 6, wm = (wv & 1)*64, wn = (wv >> 1)*64;
  int m0 = blockIdx.x*128, n0 = blockIdx.y*128;

  f32x4 acc[4][4] = {};
  gemm128_loop(x + (size_t)m0*DMODEL, w + (size_t)n0*DMODEL, abuf, bbuf, tid, acc);

  int mbase = m0 + wm, nbase = n0 + wn;
  #pragma unroll
  for (int ni = 0; ni < 4; ++ni){
    int n = nbase + ni*16 + r;
    float bv = bias[n];
    #pragma unroll
    for (int mi = 0; mi < 4; ++mi){
      #pragma unroll
      for (int reg = 0; reg < 4; ++reg){
        int m = mbase + mi*16 + quad*4 + reg;
        out[(size_t)m*DMODEL + n] = acc[mi][ni][reg] + bv;
      }
    }
  }
}

extern "C" void kernel_launch(void* const* d_in, const int* in_sizes, int n_in,
                              void* d_out, int out_size, void* d_ws, size_t ws_size,
                              hipStream_t stream) {
  (void)in_sizes; (void)n_in; (void)out_size; (void)ws_size;
  const float* query = (const float*)d_in[0];
  const float* key   = (const float*)d_in[1];
  const float* value = (const float*)d_in[2];
  const int*   mask  = (const int*)d_in[3];
  const float* w_in  = (const float*)d_in[4];
  const float* b_in  = (const float*)d_in[5];
  const float* w_out = (const float*)d_in[6];
  const float* b_out = (const float*)d_in[7];
  float* out = (float*)d_out;

  const size_t TSZ = (size_t)BATCH*NHEADS*S_LEN*DKH;
  const size_t XSZ = (size_t)S_LEN*BATCH*DMODEL;
  u16* q_ws  = (u16*)d_ws;
  u16* k_ws  = q_ws  + TSZ;
  u16* vt_ws = k_ws  + TSZ;
  u16* x_ws  = vt_ws + TSZ;
  u16* xq_bf = x_ws  + XSZ;
  u16* xk_bf = xq_bf + XSZ;
  u16* xv_bf = xk_bf + XSZ;
  u16* wi_bf = xv_bf + XSZ;
  u16* wo_bf = wi_bf + (size_t)3*DMODEL*DMODEL;
  u64* mb_ws = (u64*)(wo_bf + (size_t)DMODEL*DMODEL);

  cvt_kernel<<<1024, 256, 0, stream>>>(query, key, value, w_in, w_out, mask,
                                       xq_bf, xk_bf, xv_bf, wi_bf, wo_bf, mb_ws);
  qkv_proj_kernel<<<dim3(32, 24), 256, 0, stream>>>(xq_bf, xk_bf, xv_bf, wi_bf, b_in,
                                                    q_ws, k_ws, vt_ws);
  attn_kernel<<<dim3(16, 32), 512, 0, stream>>>(q_ws, k_ws, vt_ws, mb_ws, x_ws);
  out_proj_kernel<<<dim3(32, 8), 256, 0, stream>>>(x_ws, wo_bf, b_out, out);
}